// Round 2
// baseline (219669.409 us; speedup 1.0000x reference)
//
#include <hip/hip_runtime.h>
#include <hip/hip_bf16.h>
#include <math.h>

#define B 8
#define T 1024
#define D 1024
#define H 16
#define DH 64
#define NSTEPS 4

#define NCHAIN 2            // batch split into 2 independent chains of 4 rows
#define NBLK_CHAIN 128      // blocks per chain
#define DIMS_PER_BLK 8      // 128 * 8 = 1024 dims

__device__ __forceinline__ float sigmoidf_(float x) { return 1.0f / (1.0f + expf(-x)); }

// ---------------------------------------------------------------------------
// Generic tiled fp32 GEMM: C[M,N] = A[M,K] @ W[N,K]^T + bias[N]
// MODE 0: C[m*N + n]
// MODE 1: qkv scatter to q/k/v [B*H, T, DH]
// ---------------------------------------------------------------------------
template <int MODE>
__global__ __launch_bounds__(256) void gemm_kernel(
    const float* __restrict__ A, const float* __restrict__ W,
    const float* __restrict__ bias, float* __restrict__ C,
    int M, int N, int K, int ldw, int koff,
    float* __restrict__ qb, float* __restrict__ kb, float* __restrict__ vb)
{
    __shared__ float As[32][68];
    __shared__ float Ws[32][68];
    const int m0 = blockIdx.x * 64, n0 = blockIdx.y * 64;
    const int tid = threadIdx.x;
    const int tn = tid & 15, tm = tid >> 4;
    float acc[4][4] = {};

    for (int k0 = 0; k0 < K; k0 += 32) {
#pragma unroll
        for (int j = 0; j < 2; ++j) {
            int lin = tid + j * 256;
            int r = lin >> 3, c4 = lin & 7;
            float4 av = *(const float4*)(A + (size_t)(m0 + r) * K + k0 + c4 * 4);
            As[c4 * 4 + 0][r] = av.x; As[c4 * 4 + 1][r] = av.y;
            As[c4 * 4 + 2][r] = av.z; As[c4 * 4 + 3][r] = av.w;
            float4 wv = *(const float4*)(W + (size_t)(n0 + r) * ldw + koff + k0 + c4 * 4);
            Ws[c4 * 4 + 0][r] = wv.x; Ws[c4 * 4 + 1][r] = wv.y;
            Ws[c4 * 4 + 2][r] = wv.z; Ws[c4 * 4 + 3][r] = wv.w;
        }
        __syncthreads();
#pragma unroll
        for (int k = 0; k < 32; ++k) {
            float a_[4], b_[4];
            *(float4*)a_ = *(const float4*)&As[k][tm * 4];
            *(float4*)b_ = *(const float4*)&Ws[k][tn * 4];
#pragma unroll
            for (int i = 0; i < 4; ++i)
#pragma unroll
                for (int j = 0; j < 4; ++j) acc[i][j] += a_[i] * b_[j];
        }
        __syncthreads();
    }

#pragma unroll
    for (int i = 0; i < 4; ++i) {
        int m = m0 + tm * 4 + i;
#pragma unroll
        for (int j = 0; j < 4; ++j) {
            int n = n0 + tn * 4 + j;
            float v = acc[i][j] + bias[n];
            if (MODE == 0) {
                C[(size_t)m * N + n] = v;
            } else {
                int which = n >> 10;
                int hh = (n & 1023) >> 6;
                int dh = n & 63;
                int b = m >> 10, t = m & 1023;
                float* dst = (which == 0) ? qb : ((which == 1) ? kb : vb);
                dst[(((size_t)(b * H + hh)) * T + t) * DH + dh] = v;
            }
        }
    }
}

// ---------------------------------------------------------------------------
// Flash attention fp32 (unchanged from R0)
// ---------------------------------------------------------------------------
__global__ __launch_bounds__(256) void attn_kernel(
    const float* __restrict__ qb, const float* __restrict__ kb,
    const float* __restrict__ vb, float* __restrict__ ctx)
{
    __shared__ float Qs[64][65];
    __shared__ float Ks[64][65];
    __shared__ float Vs[64][65];
    __shared__ float mrow[64], lrow[64], srow[64];
    __shared__ float tred[64][4];

    const int tid = threadIdx.x;
    const int row = tid & 63, seg = tid >> 6;
    const int bx = blockIdx.x;
    const int qblk = bx & 15;
    const int bh = bx >> 4;
    const float* qp = qb + (size_t)bh * T * DH;
    const float* kp = kb + (size_t)bh * T * DH;
    const float* vp = vb + (size_t)bh * T * DH;

#pragma unroll
    for (int i = 0; i < 4; ++i) {
        int lin = tid + i * 256;
        int r = lin >> 4, c4 = lin & 15;
        float4 v = *(const float4*)(qp + (size_t)(qblk * 64 + r) * DH + c4 * 4);
        Qs[r][c4 * 4 + 0] = v.x; Qs[r][c4 * 4 + 1] = v.y;
        Qs[r][c4 * 4 + 2] = v.z; Qs[r][c4 * 4 + 3] = v.w;
    }
    if (tid < 64) { mrow[tid] = -3.0e38f; lrow[tid] = 0.0f; }

    float Oacc[16];
#pragma unroll
    for (int j = 0; j < 16; ++j) Oacc[j] = 0.0f;

    for (int kt = 0; kt < 16; ++kt) {
        __syncthreads();
#pragma unroll
        for (int i = 0; i < 4; ++i) {
            int lin = tid + i * 256;
            int r = lin >> 4, c4 = lin & 15;
            float4 kv = *(const float4*)(kp + (size_t)(kt * 64 + r) * DH + c4 * 4);
            Ks[r][c4 * 4 + 0] = kv.x; Ks[r][c4 * 4 + 1] = kv.y;
            Ks[r][c4 * 4 + 2] = kv.z; Ks[r][c4 * 4 + 3] = kv.w;
            float4 vv = *(const float4*)(vp + (size_t)(kt * 64 + r) * DH + c4 * 4);
            Vs[r][c4 * 4 + 0] = vv.x; Vs[r][c4 * 4 + 1] = vv.y;
            Vs[r][c4 * 4 + 2] = vv.z; Vs[r][c4 * 4 + 3] = vv.w;
        }
        __syncthreads();

        float sacc[16];
#pragma unroll
        for (int j = 0; j < 16; ++j) sacc[j] = 0.0f;
        for (int k = 0; k < 64; ++k) {
            float qv = Qs[row][k];
#pragma unroll
            for (int j = 0; j < 16; ++j) sacc[j] += qv * Ks[seg * 16 + j][k];
        }
        float tmax = -3.0e38f;
#pragma unroll
        for (int j = 0; j < 16; ++j) { sacc[j] *= 0.125f; tmax = fmaxf(tmax, sacc[j]); }
        tred[row][seg] = tmax;
        __syncthreads();
        if (seg == 0) {
            float mt = fmaxf(fmaxf(tred[row][0], tred[row][1]),
                             fmaxf(tred[row][2], tred[row][3]));
            float mo = mrow[row];
            float mn = fmaxf(mo, mt);
            srow[row] = expf(mo - mn);
            mrow[row] = mn;
        }
        __syncthreads();
        float mn = mrow[row], sc = srow[row];
        float psum = 0.0f;
#pragma unroll
        for (int j = 0; j < 16; ++j) {
            float p = expf(sacc[j] - mn);
            Ks[row][seg * 16 + j] = p;
            psum += p;
        }
        tred[row][seg] = psum;
#pragma unroll
        for (int j = 0; j < 16; ++j) Oacc[j] *= sc;
        __syncthreads();
        if (seg == 0)
            lrow[row] = lrow[row] * sc +
                        (tred[row][0] + tred[row][1] + tred[row][2] + tred[row][3]);
        for (int kj = 0; kj < 64; ++kj) {
            float pv = Ks[row][kj];
#pragma unroll
            for (int j = 0; j < 16; ++j) Oacc[j] += pv * Vs[kj][seg * 16 + j];
        }
    }
    __syncthreads();
    float linv = 1.0f / lrow[row];
    int b = bh >> 4, hh = bh & 15;
    int q = qblk * 64 + row;
#pragma unroll
    for (int j = 0; j < 16; ++j)
        ctx[((size_t)(b * T + q)) * D + hh * 64 + seg * 16 + j] = Oacc[j] * linv;
}

// ---------------------------------------------------------------------------
// Persistent GRU recurrence. Grid = 256 blocks x 256 threads, 1 block/CU
// (128 KB LDS). Chain c = blockIdx&1 owns batch rows [c*4, c*4+4); the
// chain's 128 blocks sync via an all-to-all flag barrier (agent scope).
// Each block owns 8 output dims; its 32 weight rows (w_hh r/z/n + gate_w
// left half) stay resident in LDS for all 4096 steps.
// ---------------------------------------------------------------------------
__device__ __forceinline__ void chain_barrier(unsigned* __restrict__ flagbase,
                                              int pos, unsigned k, int tid)
{
    __syncthreads();                    // all block writes done
    if (tid == 0) {
        __threadfence();                // release our writes to agent scope
        __hip_atomic_store(flagbase + pos * 16, k,
                           __ATOMIC_RELEASE, __HIP_MEMORY_SCOPE_AGENT);
    }
    if (tid < NBLK_CHAIN) {
        while (__hip_atomic_load(flagbase + tid * 16,
                                 __ATOMIC_RELAXED, __HIP_MEMORY_SCOPE_AGENT) < k)
            __builtin_amdgcn_s_sleep(1);
    }
    __threadfence();                    // acquire
    __syncthreads();
}

__global__ __launch_bounds__(256, 1) void gru_persistent(
    const float* __restrict__ w_hh, const float* __restrict__ b_hh,
    const float* __restrict__ gate_w,
    const float* __restrict__ gi, const float* __restrict__ ga,
    const float* __restrict__ attn, float* __restrict__ out,
    float* __restrict__ hbuf, float* __restrict__ hpbuf,
    unsigned* __restrict__ flags)
{
    extern __shared__ float lds[];      // 32 rows x 1024 floats = 128 KB
    const int tid = threadIdx.x;
    const int chain = blockIdx.x & 1;
    const int pos = blockIdx.x >> 1;            // 0..127
    const int d0 = pos * DIMS_PER_BLK;

    // --- load resident weights: rows 0..7 = w_r, 8..15 = w_z, 16..23 = w_n,
    //     24..31 = gate_w[:, :D] for dims d0..d0+7
#pragma unroll 4
    for (int r = 0; r < 32; ++r) {
        int which = r >> 3, j = r & 7;
        const float* src = (which < 3)
            ? (w_hh + (size_t)(which * D + d0 + j) * D)
            : (gate_w + (size_t)(d0 + j) * (2 * D));
        float4 v = *(const float4*)(src + tid * 4);
        *(float4*)(&lds[(size_t)r * 1024 + tid * 4]) = v;
    }
    __syncthreads();

    // thread layout for the dot phases: 32 groups of 8 lanes
    const int grp = tid >> 3, kp = tid & 7;
    const int bl = grp & 3, j = grp >> 2;       // batch-in-chain, dim-in-block
    const int bg = chain * 4 + bl;              // global batch row
    const int d = d0 + j;
    const float* wr = lds + (0 * 8 + j) * 1024;
    const float* wz = lds + (8 + j) * 1024;
    const float* wn = lds + (16 + j) * 1024;
    const float* wg = lds + (24 + j) * 1024;
    unsigned* flagbase = flags + chain * NBLK_CHAIN * 16;

    const float bhr = b_hh[d], bhz = b_hh[D + d], bhn = b_hh[2 * D + d];

    unsigned bar = 0;
    for (int t = 0; t < T; ++t) {
        const float* gib = gi + ((size_t)bg * T + t) * (3 * D);
        const float gav_a = ga[((size_t)bg * T + t) * D + d];
        const float av = attn[((size_t)bg * T + t) * D + d];
        for (int s = 0; s < NSTEPS; ++s) {
            // ---- phase A: gh = h @ w_hh^T (this block's 8 dims, 4 b rows)
            const float* hrow = hbuf + bg * D;
            float ar = 0.0f, az = 0.0f, an = 0.0f;
#pragma unroll 8
            for (int m = 0; m < 32; ++m) {
                int kk = (kp + 8 * m) * 4;      // bank-spread k chunks
                float4 hv = *(const float4*)(hrow + kk);
                float4 w0 = *(const float4*)(wr + kk);
                float4 w1 = *(const float4*)(wz + kk);
                float4 w2 = *(const float4*)(wn + kk);
                ar += hv.x * w0.x + hv.y * w0.y + hv.z * w0.z + hv.w * w0.w;
                az += hv.x * w1.x + hv.y * w1.y + hv.z * w1.z + hv.w * w1.w;
                an += hv.x * w2.x + hv.y * w2.y + hv.z * w2.z + hv.w * w2.w;
            }
#pragma unroll
            for (int off = 1; off < 8; off <<= 1) {
                ar += __shfl_xor(ar, off);
                az += __shfl_xor(az, off);
                an += __shfl_xor(an, off);
            }
            if (kp == 0) {
                float r_ = sigmoidf_(gib[d] + ar + bhr);
                float z_ = sigmoidf_(gib[D + d] + az + bhz);
                float n_ = tanhf(gib[2 * D + d] + r_ * (an + bhn));
                float ho = hbuf[bg * D + d];
                hpbuf[bg * D + d] = (1.0f - z_) * n_ + z_ * ho;
            }
            chain_barrier(flagbase, pos, ++bar, tid);

            // ---- phase B: g = sigmoid(hp @ gwL^T + ga); h = g*hp + (1-g)*a
            const float* hprow = hpbuf + bg * D;
            float ag = 0.0f;
#pragma unroll 8
            for (int m = 0; m < 32; ++m) {
                int kk = (kp + 8 * m) * 4;
                float4 hv = *(const float4*)(hprow + kk);
                float4 wv = *(const float4*)(wg + kk);
                ag += hv.x * wv.x + hv.y * wv.y + hv.z * wv.z + hv.w * wv.w;
            }
#pragma unroll
            for (int off = 1; off < 8; off <<= 1) ag += __shfl_xor(ag, off);
            if (kp == 0) {
                float g = sigmoidf_(ag + gav_a);
                float hpv = hpbuf[bg * D + d];
                float hn = g * hpv + (1.0f - g) * av;
                hbuf[bg * D + d] = hn;
                if (s == NSTEPS - 1) out[((size_t)bg * T + t) * D + d] = hn;
            }
            chain_barrier(flagbase, pos, ++bar, tid);
        }
    }
}

// ---------------------------------------------------------------------------
extern "C" void kernel_launch(void* const* d_in, const int* in_sizes, int n_in,
                              void* d_out, int out_size, void* d_ws, size_t ws_size,
                              hipStream_t stream)
{
    const float* x          = (const float*)d_in[0];
    const float* in_proj_w  = (const float*)d_in[1];
    const float* in_proj_b  = (const float*)d_in[2];
    const float* out_proj_w = (const float*)d_in[3];
    const float* out_proj_b = (const float*)d_in[4];
    const float* w_ih       = (const float*)d_in[5];
    const float* w_hh       = (const float*)d_in[6];
    const float* b_ih       = (const float*)d_in[7];
    const float* b_hh       = (const float*)d_in[8];
    const float* gate_w     = (const float*)d_in[9];
    const float* gate_b     = (const float*)d_in[10];
    float* out = (float*)d_out;

    float* ws = (float*)d_ws;
    const size_t S1 = (size_t)B * H * T * DH;   // 8,388,608 floats
    float* qb   = ws;
    float* kb   = ws + S1;
    float* vb   = ws + 2 * S1;
    float* ctx  = ws + 3 * S1;
    float* attn = ws + 4 * S1;
    float* ga   = ws + 5 * S1;
    float* gi   = ws;                           // overlaps q/k/v
    float* hbuf  = ws + 6 * S1;
    float* hpbuf = hbuf + B * D;
    unsigned* flags = (unsigned*)(hpbuf + B * D);   // 256 slots * 16 u32

    dim3 blk(256);

    // front: qkv -> attention -> out_proj -> gate-attn-half -> gi
    gemm_kernel<1><<<dim3(128, 48), blk, 0, stream>>>(
        x, in_proj_w, in_proj_b, nullptr, B * T, 3 * D, D, D, 0, qb, kb, vb);
    attn_kernel<<<dim3(2048), blk, 0, stream>>>(qb, kb, vb, ctx);
    gemm_kernel<0><<<dim3(128, 16), blk, 0, stream>>>(
        ctx, out_proj_w, out_proj_b, attn, B * T, D, D, D, 0,
        nullptr, nullptr, nullptr);
    gemm_kernel<0><<<dim3(128, 16), blk, 0, stream>>>(
        attn, gate_w, gate_b, ga, B * T, D, D, 2 * D, D,
        nullptr, nullptr, nullptr);
    gemm_kernel<0><<<dim3(128, 48), blk, 0, stream>>>(
        x, w_ih, b_ih, gi, B * T, 3 * D, D, D, 0,
        nullptr, nullptr, nullptr);

    // zero h and barrier flags every launch (graph-replay deterministic)
    hipMemsetAsync(hbuf, 0,
                   (2 * (size_t)B * D + NCHAIN * NBLK_CHAIN * 16) * sizeof(float),
                   stream);

    static bool attr_done = false;
    if (!attr_done) {
        hipFuncSetAttribute((const void*)gru_persistent,
                            hipFuncAttributeMaxDynamicSharedMemorySize, 131072);
        attr_done = true;
    }
    gru_persistent<<<dim3(NCHAIN * NBLK_CHAIN), blk, 131072, stream>>>(
        w_hh, b_hh, gate_w, gi, ga, attn, out, hbuf, hpbuf, flags);
}

// Round 3
// 59648.462 us; speedup vs baseline: 3.6827x; 3.6827x over previous
//
#include <hip/hip_runtime.h>
#include <hip/hip_bf16.h>
#include <math.h>

#define B 8
#define T 1024
#define D 1024
#define H 16
#define DH 64
#define NSTEPS 4

#define NCHAIN 2            // batch split into 2 independent chains of 4 rows
#define NBLK_CHAIN 128      // blocks per chain
#define DIMS_PER_BLK 8      // 128 * 8 = 1024 dims

#define STG_PITCH 1032      // 1024 + 8 pad words: rows land on banks 0/8/16/24

__device__ __forceinline__ float sigmoidf_(float x) { return 1.0f / (1.0f + expf(-x)); }

// ---------------------------------------------------------------------------
// Generic tiled fp32 GEMM: C[M,N] = A[M,K] @ W[N,K]^T + bias[N]
// MODE 0: C[m*N + n]
// MODE 1: qkv scatter to q/k/v [B*H, T, DH]
// ---------------------------------------------------------------------------
template <int MODE>
__global__ __launch_bounds__(256) void gemm_kernel(
    const float* __restrict__ A, const float* __restrict__ W,
    const float* __restrict__ bias, float* __restrict__ C,
    int M, int N, int K, int ldw, int koff,
    float* __restrict__ qb, float* __restrict__ kb, float* __restrict__ vb)
{
    __shared__ float As[32][68];
    __shared__ float Ws[32][68];
    const int m0 = blockIdx.x * 64, n0 = blockIdx.y * 64;
    const int tid = threadIdx.x;
    const int tn = tid & 15, tm = tid >> 4;
    float acc[4][4] = {};

    for (int k0 = 0; k0 < K; k0 += 32) {
#pragma unroll
        for (int j = 0; j < 2; ++j) {
            int lin = tid + j * 256;
            int r = lin >> 3, c4 = lin & 7;
            float4 av = *(const float4*)(A + (size_t)(m0 + r) * K + k0 + c4 * 4);
            As[c4 * 4 + 0][r] = av.x; As[c4 * 4 + 1][r] = av.y;
            As[c4 * 4 + 2][r] = av.z; As[c4 * 4 + 3][r] = av.w;
            float4 wv = *(const float4*)(W + (size_t)(n0 + r) * ldw + koff + k0 + c4 * 4);
            Ws[c4 * 4 + 0][r] = wv.x; Ws[c4 * 4 + 1][r] = wv.y;
            Ws[c4 * 4 + 2][r] = wv.z; Ws[c4 * 4 + 3][r] = wv.w;
        }
        __syncthreads();
#pragma unroll
        for (int k = 0; k < 32; ++k) {
            float a_[4], b_[4];
            *(float4*)a_ = *(const float4*)&As[k][tm * 4];
            *(float4*)b_ = *(const float4*)&Ws[k][tn * 4];
#pragma unroll
            for (int i = 0; i < 4; ++i)
#pragma unroll
                for (int j = 0; j < 4; ++j) acc[i][j] += a_[i] * b_[j];
        }
        __syncthreads();
    }

#pragma unroll
    for (int i = 0; i < 4; ++i) {
        int m = m0 + tm * 4 + i;
#pragma unroll
        for (int j = 0; j < 4; ++j) {
            int n = n0 + tn * 4 + j;
            float v = acc[i][j] + bias[n];
            if (MODE == 0) {
                C[(size_t)m * N + n] = v;
            } else {
                int which = n >> 10;
                int hh = (n & 1023) >> 6;
                int dh = n & 63;
                int b = m >> 10, t = m & 1023;
                float* dst = (which == 0) ? qb : ((which == 1) ? kb : vb);
                dst[(((size_t)(b * H + hh)) * T + t) * DH + dh] = v;
            }
        }
    }
}

// ---------------------------------------------------------------------------
// Flash attention fp32 (unchanged)
// ---------------------------------------------------------------------------
__global__ __launch_bounds__(256) void attn_kernel(
    const float* __restrict__ qb, const float* __restrict__ kb,
    const float* __restrict__ vb, float* __restrict__ ctx)
{
    __shared__ float Qs[64][65];
    __shared__ float Ks[64][65];
    __shared__ float Vs[64][65];
    __shared__ float mrow[64], lrow[64], srow[64];
    __shared__ float tred[64][4];

    const int tid = threadIdx.x;
    const int row = tid & 63, seg = tid >> 6;
    const int bx = blockIdx.x;
    const int qblk = bx & 15;
    const int bh = bx >> 4;
    const float* qp = qb + (size_t)bh * T * DH;
    const float* kp = kb + (size_t)bh * T * DH;
    const float* vp = vb + (size_t)bh * T * DH;

#pragma unroll
    for (int i = 0; i < 4; ++i) {
        int lin = tid + i * 256;
        int r = lin >> 4, c4 = lin & 15;
        float4 v = *(const float4*)(qp + (size_t)(qblk * 64 + r) * DH + c4 * 4);
        Qs[r][c4 * 4 + 0] = v.x; Qs[r][c4 * 4 + 1] = v.y;
        Qs[r][c4 * 4 + 2] = v.z; Qs[r][c4 * 4 + 3] = v.w;
    }
    if (tid < 64) { mrow[tid] = -3.0e38f; lrow[tid] = 0.0f; }

    float Oacc[16];
#pragma unroll
    for (int j = 0; j < 16; ++j) Oacc[j] = 0.0f;

    for (int kt = 0; kt < 16; ++kt) {
        __syncthreads();
#pragma unroll
        for (int i = 0; i < 4; ++i) {
            int lin = tid + i * 256;
            int r = lin >> 4, c4 = lin & 15;
            float4 kv = *(const float4*)(kp + (size_t)(kt * 64 + r) * DH + c4 * 4);
            Ks[r][c4 * 4 + 0] = kv.x; Ks[r][c4 * 4 + 1] = kv.y;
            Ks[r][c4 * 4 + 2] = kv.z; Ks[r][c4 * 4 + 3] = kv.w;
            float4 vv = *(const float4*)(vp + (size_t)(kt * 64 + r) * DH + c4 * 4);
            Vs[r][c4 * 4 + 0] = vv.x; Vs[r][c4 * 4 + 1] = vv.y;
            Vs[r][c4 * 4 + 2] = vv.z; Vs[r][c4 * 4 + 3] = vv.w;
        }
        __syncthreads();

        float sacc[16];
#pragma unroll
        for (int j = 0; j < 16; ++j) sacc[j] = 0.0f;
        for (int k = 0; k < 64; ++k) {
            float qv = Qs[row][k];
#pragma unroll
            for (int j = 0; j < 16; ++j) sacc[j] += qv * Ks[seg * 16 + j][k];
        }
        float tmax = -3.0e38f;
#pragma unroll
        for (int j = 0; j < 16; ++j) { sacc[j] *= 0.125f; tmax = fmaxf(tmax, sacc[j]); }
        tred[row][seg] = tmax;
        __syncthreads();
        if (seg == 0) {
            float mt = fmaxf(fmaxf(tred[row][0], tred[row][1]),
                             fmaxf(tred[row][2], tred[row][3]));
            float mo = mrow[row];
            float mn = fmaxf(mo, mt);
            srow[row] = expf(mo - mn);
            mrow[row] = mn;
        }
        __syncthreads();
        float mn = mrow[row], sc = srow[row];
        float psum = 0.0f;
#pragma unroll
        for (int j = 0; j < 16; ++j) {
            float p = expf(sacc[j] - mn);
            Ks[row][seg * 16 + j] = p;
            psum += p;
        }
        tred[row][seg] = psum;
#pragma unroll
        for (int j = 0; j < 16; ++j) Oacc[j] *= sc;
        __syncthreads();
        if (seg == 0)
            lrow[row] = lrow[row] * sc +
                        (tred[row][0] + tred[row][1] + tred[row][2] + tred[row][3]);
        for (int kj = 0; kj < 64; ++kj) {
            float pv = Ks[row][kj];
#pragma unroll
            for (int j = 0; j < 16; ++j) Oacc[j] += pv * Vs[kj][seg * 16 + j];
        }
    }
    __syncthreads();
    float linv = 1.0f / lrow[row];
    int b = bh >> 4, hh = bh & 15;
    int q = qblk * 64 + row;
#pragma unroll
    for (int j = 0; j < 16; ++j)
        ctx[((size_t)(b * T + q)) * D + hh * 64 + seg * 16 + j] = Oacc[j] * linv;
}

// ---------------------------------------------------------------------------
// Persistent GRU recurrence, fence-free protocol:
//  - h/hp cross-block bytes ONLY move via relaxed agent-scope atomics
//    (sc1 -> write-through / read-around the non-coherent per-XCD L2).
//  - producer: store -> s_waitcnt vmcnt(0) -> __syncthreads -> tid0 counter++
//  - consumer: tid0 polls counter -> __syncthreads -> stage 16KB into LDS
// No __threadfence anywhere (that was the 26us/barrier killer in R1).
// ---------------------------------------------------------------------------
__device__ __forceinline__ void stage_rows(const float* __restrict__ src,
                                           float* __restrict__ sh, int tid)
{
    float r[16];
#pragma unroll
    for (int q = 0; q < 16; ++q)
        r[q] = __hip_atomic_load(src + q * 256 + tid, __ATOMIC_RELAXED,
                                 __HIP_MEMORY_SCOPE_AGENT);
#pragma unroll
    for (int q = 0; q < 16; ++q) {
        int w = q * 256 + tid;
        sh[(w >> 10) * STG_PITCH + (w & 1023)] = r[q];
    }
}

__device__ __forceinline__ void arrive_and_wait(unsigned* __restrict__ cnt,
                                                unsigned target, int tid)
{
    __syncthreads();        // all waves drained their uncached stores (vmcnt)
    if (tid == 0) {
        __hip_atomic_fetch_add(cnt, 1u, __ATOMIC_RELAXED,
                               __HIP_MEMORY_SCOPE_AGENT);
        while (__hip_atomic_load(cnt, __ATOMIC_RELAXED,
                                 __HIP_MEMORY_SCOPE_AGENT) < target)
            __builtin_amdgcn_s_sleep(1);
    }
    __syncthreads();
}

__global__ __launch_bounds__(256, 1) void gru_persistent(
    const float* __restrict__ w_hh, const float* __restrict__ b_hh,
    const float* __restrict__ gate_w,
    const float* __restrict__ gi, const float* __restrict__ ga,
    const float* __restrict__ attn, float* __restrict__ out,
    float* __restrict__ hbuf, float* __restrict__ hpbuf,
    unsigned* __restrict__ counters)
{
    extern __shared__ float lds[];   // [0,32768): weights; [32768,+4*1032): stage
    float* sh = lds + 32768;
    const int tid = threadIdx.x;
    const int chain = blockIdx.x & 1;
    const int pos = blockIdx.x >> 1;            // 0..127
    const int d0 = pos * DIMS_PER_BLK;

    // resident weights: rows 0..7 w_r, 8..15 w_z, 16..23 w_n, 24..31 gate_wL
#pragma unroll 4
    for (int r = 0; r < 32; ++r) {
        int which = r >> 3, j = r & 7;
        const float* src = (which < 3)
            ? (w_hh + (size_t)(which * D + d0 + j) * D)
            : (gate_w + (size_t)(d0 + j) * (2 * D));
        float4 v = *(const float4*)(src + tid * 4);
        *(float4*)(&lds[(size_t)r * 1024 + tid * 4]) = v;
    }

    const int grp = tid >> 3, kp = tid & 7;
    const int bl = grp & 3, j = grp >> 2;       // batch-in-chain, dim-in-block
    const int bg = chain * 4 + bl;              // global batch row
    const int d = d0 + j;
    const float* wr = lds + (0 * 8 + j) * 1024;
    const float* wz = lds + (8 + j) * 1024;
    const float* wn = lds + (16 + j) * 1024;
    const float* wg = lds + (24 + j) * 1024;
    const float* hrow_sh = sh + bl * STG_PITCH;

    unsigned* cnt = counters + chain * 64;
    const float* hsrc  = hbuf  + (size_t)chain * 4 * D;
    const float* hpsrc = hpbuf + (size_t)chain * 4 * D;

    const float bhr = b_hh[d], bhz = b_hh[D + d], bhn = b_hh[2 * D + d];

    unsigned bar = 0;
    float hpv = 0.0f;                 // own-dim h' carried A->B in register
    for (int t = 0; t < T; ++t) {
        const float* gib = gi + ((size_t)bg * T + t) * (3 * D);
        const float gav_a = ga[((size_t)bg * T + t) * D + d];
        const float av = attn[((size_t)bg * T + t) * D + d];
        for (int s = 0; s < NSTEPS; ++s) {
            // ---- stage h (uncached) into LDS, then phase A
            stage_rows(hsrc, sh, tid);
            __syncthreads();
            float ar = 0.0f, az = 0.0f, an = 0.0f;
#pragma unroll 8
            for (int m = 0; m < 32; ++m) {
                int kk = (kp + 8 * m) * 4;
                float4 hv = *(const float4*)(hrow_sh + kk);
                float4 w0 = *(const float4*)(wr + kk);
                float4 w1 = *(const float4*)(wz + kk);
                float4 w2 = *(const float4*)(wn + kk);
                ar += hv.x * w0.x + hv.y * w0.y + hv.z * w0.z + hv.w * w0.w;
                az += hv.x * w1.x + hv.y * w1.y + hv.z * w1.z + hv.w * w1.w;
                an += hv.x * w2.x + hv.y * w2.y + hv.z * w2.z + hv.w * w2.w;
            }
#pragma unroll
            for (int off = 1; off < 8; off <<= 1) {
                ar += __shfl_xor(ar, off);
                az += __shfl_xor(az, off);
                an += __shfl_xor(an, off);
            }
            if (kp == 0) {
                float r_ = sigmoidf_(gib[d] + ar + bhr);
                float z_ = sigmoidf_(gib[D + d] + az + bhz);
                float n_ = tanhf(gib[2 * D + d] + r_ * (an + bhn));
                float ho = hrow_sh[d];
                hpv = (1.0f - z_) * n_ + z_ * ho;
                __hip_atomic_store(hpbuf + (size_t)bg * D + d, hpv,
                                   __ATOMIC_RELAXED, __HIP_MEMORY_SCOPE_AGENT);
            }
            asm volatile("s_waitcnt vmcnt(0)" ::: "memory");
            arrive_and_wait(cnt, (++bar) * NBLK_CHAIN, tid);

            // ---- stage hp (uncached) into LDS, then phase B
            stage_rows(hpsrc, sh, tid);
            __syncthreads();
            float ag = 0.0f;
#pragma unroll 8
            for (int m = 0; m < 32; ++m) {
                int kk = (kp + 8 * m) * 4;
                float4 hv = *(const float4*)(hrow_sh + kk);
                float4 wv = *(const float4*)(wg + kk);
                ag += hv.x * wv.x + hv.y * wv.y + hv.z * wv.z + hv.w * wv.w;
            }
#pragma unroll
            for (int off = 1; off < 8; off <<= 1) ag += __shfl_xor(ag, off);
            if (kp == 0) {
                float g = sigmoidf_(ag + gav_a);
                float hn = g * hpv + (1.0f - g) * av;
                __hip_atomic_store(hbuf + (size_t)bg * D + d, hn,
                                   __ATOMIC_RELAXED, __HIP_MEMORY_SCOPE_AGENT);
                if (s == NSTEPS - 1) out[((size_t)bg * T + t) * D + d] = hn;
            }
            asm volatile("s_waitcnt vmcnt(0)" ::: "memory");
            arrive_and_wait(cnt, (++bar) * NBLK_CHAIN, tid);
        }
    }
}

// ---------------------------------------------------------------------------
extern "C" void kernel_launch(void* const* d_in, const int* in_sizes, int n_in,
                              void* d_out, int out_size, void* d_ws, size_t ws_size,
                              hipStream_t stream)
{
    const float* x          = (const float*)d_in[0];
    const float* in_proj_w  = (const float*)d_in[1];
    const float* in_proj_b  = (const float*)d_in[2];
    const float* out_proj_w = (const float*)d_in[3];
    const float* out_proj_b = (const float*)d_in[4];
    const float* w_ih       = (const float*)d_in[5];
    const float* w_hh       = (const float*)d_in[6];
    const float* b_ih       = (const float*)d_in[7];
    const float* b_hh       = (const float*)d_in[8];
    const float* gate_w     = (const float*)d_in[9];
    const float* gate_b     = (const float*)d_in[10];
    float* out = (float*)d_out;

    float* ws = (float*)d_ws;
    const size_t S1 = (size_t)B * H * T * DH;   // 8,388,608 floats
    float* qb   = ws;
    float* kb   = ws + S1;
    float* vb   = ws + 2 * S1;
    float* ctx  = ws + 3 * S1;
    float* attn = ws + 4 * S1;
    float* ga   = ws + 5 * S1;
    float* gi   = ws;                           // overlaps q/k/v
    float* hbuf  = ws + 6 * S1;
    float* hpbuf = hbuf + B * D;
    unsigned* counters = (unsigned*)(hpbuf + B * D);   // 2 chains * 64 u32

    dim3 blk(256);

    gemm_kernel<1><<<dim3(128, 48), blk, 0, stream>>>(
        x, in_proj_w, in_proj_b, nullptr, B * T, 3 * D, D, D, 0, qb, kb, vb);
    attn_kernel<<<dim3(2048), blk, 0, stream>>>(qb, kb, vb, ctx);
    gemm_kernel<0><<<dim3(128, 16), blk, 0, stream>>>(
        ctx, out_proj_w, out_proj_b, attn, B * T, D, D, D, 0,
        nullptr, nullptr, nullptr);
    gemm_kernel<0><<<dim3(128, 16), blk, 0, stream>>>(
        attn, gate_w, gate_b, ga, B * T, D, D, 2 * D, D,
        nullptr, nullptr, nullptr);
    gemm_kernel<0><<<dim3(128, 48), blk, 0, stream>>>(
        x, w_ih, b_ih, gi, B * T, 3 * D, D, D, 0,
        nullptr, nullptr, nullptr);

    // zero h, hp, and counters every launch (graph-replay deterministic)
    hipMemsetAsync(hbuf, 0, (2 * (size_t)B * D) * sizeof(float) + 512, stream);

    const int LDS_BYTES = (32 * 1024 + 4 * STG_PITCH) * 4;   // 147,584
    static bool attr_done = false;
    if (!attr_done) {
        hipFuncSetAttribute((const void*)gru_persistent,
                            hipFuncAttributeMaxDynamicSharedMemorySize, LDS_BYTES);
        attr_done = true;
    }
    gru_persistent<<<dim3(NCHAIN * NBLK_CHAIN), blk, LDS_BYTES, stream>>>(
        w_hh, b_hh, gate_w, gi, ga, attn, out, hbuf, hpbuf, counters);
}

// Round 4
// 43326.486 us; speedup vs baseline: 5.0701x; 1.3767x over previous
//
#include <hip/hip_runtime.h>
#include <hip/hip_bf16.h>
#include <math.h>

#define B 8
#define T 1024
#define D 1024
#define H 16
#define DH 64
#define NSTEPS 4

#define NCHAIN 2            // batch split into 2 independent chains of 4 rows
#define NBLK_CHAIN 128      // blocks per chain
#define DIMS_PER_BLK 8      // 128 * 8 = 1024 dims

#define STG_PITCH 1032      // staging row pitch (words)
#define FLAG_STRIDE 16      // flags 64B apart (own cache line each)

__device__ __forceinline__ float sigmoidf_(float x) { return 1.0f / (1.0f + expf(-x)); }

// ---------------------------------------------------------------------------
// Generic tiled fp32 GEMM: C[M,N] = A[M,K] @ W[N,K]^T + bias[N]
// MODE 0: C[m*N + n]
// MODE 1: qkv scatter to q/k/v [B*H, T, DH]
// ---------------------------------------------------------------------------
template <int MODE>
__global__ __launch_bounds__(256) void gemm_kernel(
    const float* __restrict__ A, const float* __restrict__ W,
    const float* __restrict__ bias, float* __restrict__ C,
    int M, int N, int K, int ldw, int koff,
    float* __restrict__ qb, float* __restrict__ kb, float* __restrict__ vb)
{
    __shared__ float As[32][68];
    __shared__ float Ws[32][68];
    const int m0 = blockIdx.x * 64, n0 = blockIdx.y * 64;
    const int tid = threadIdx.x;
    const int tn = tid & 15, tm = tid >> 4;
    float acc[4][4] = {};

    for (int k0 = 0; k0 < K; k0 += 32) {
#pragma unroll
        for (int j = 0; j < 2; ++j) {
            int lin = tid + j * 256;
            int r = lin >> 3, c4 = lin & 7;
            float4 av = *(const float4*)(A + (size_t)(m0 + r) * K + k0 + c4 * 4);
            As[c4 * 4 + 0][r] = av.x; As[c4 * 4 + 1][r] = av.y;
            As[c4 * 4 + 2][r] = av.z; As[c4 * 4 + 3][r] = av.w;
            float4 wv = *(const float4*)(W + (size_t)(n0 + r) * ldw + koff + k0 + c4 * 4);
            Ws[c4 * 4 + 0][r] = wv.x; Ws[c4 * 4 + 1][r] = wv.y;
            Ws[c4 * 4 + 2][r] = wv.z; Ws[c4 * 4 + 3][r] = wv.w;
        }
        __syncthreads();
#pragma unroll
        for (int k = 0; k < 32; ++k) {
            float a_[4], b_[4];
            *(float4*)a_ = *(const float4*)&As[k][tm * 4];
            *(float4*)b_ = *(const float4*)&Ws[k][tn * 4];
#pragma unroll
            for (int i = 0; i < 4; ++i)
#pragma unroll
                for (int j = 0; j < 4; ++j) acc[i][j] += a_[i] * b_[j];
        }
        __syncthreads();
    }

#pragma unroll
    for (int i = 0; i < 4; ++i) {
        int m = m0 + tm * 4 + i;
#pragma unroll
        for (int j = 0; j < 4; ++j) {
            int n = n0 + tn * 4 + j;
            float v = acc[i][j] + bias[n];
            if (MODE == 0) {
                C[(size_t)m * N + n] = v;
            } else {
                int which = n >> 10;
                int hh = (n & 1023) >> 6;
                int dh = n & 63;
                int b = m >> 10, t = m & 1023;
                float* dst = (which == 0) ? qb : ((which == 1) ? kb : vb);
                dst[(((size_t)(b * H + hh)) * T + t) * DH + dh] = v;
            }
        }
    }
}

// ---------------------------------------------------------------------------
// Flash attention fp32 (unchanged)
// ---------------------------------------------------------------------------
__global__ __launch_bounds__(256) void attn_kernel(
    const float* __restrict__ qb, const float* __restrict__ kb,
    const float* __restrict__ vb, float* __restrict__ ctx)
{
    __shared__ float Qs[64][65];
    __shared__ float Ks[64][65];
    __shared__ float Vs[64][65];
    __shared__ float mrow[64], lrow[64], srow[64];
    __shared__ float tred[64][4];

    const int tid = threadIdx.x;
    const int row = tid & 63, seg = tid >> 6;
    const int bx = blockIdx.x;
    const int qblk = bx & 15;
    const int bh = bx >> 4;
    const float* qp = qb + (size_t)bh * T * DH;
    const float* kp = kb + (size_t)bh * T * DH;
    const float* vp = vb + (size_t)bh * T * DH;

#pragma unroll
    for (int i = 0; i < 4; ++i) {
        int lin = tid + i * 256;
        int r = lin >> 4, c4 = lin & 15;
        float4 v = *(const float4*)(qp + (size_t)(qblk * 64 + r) * DH + c4 * 4);
        Qs[r][c4 * 4 + 0] = v.x; Qs[r][c4 * 4 + 1] = v.y;
        Qs[r][c4 * 4 + 2] = v.z; Qs[r][c4 * 4 + 3] = v.w;
    }
    if (tid < 64) { mrow[tid] = -3.0e38f; lrow[tid] = 0.0f; }

    float Oacc[16];
#pragma unroll
    for (int j = 0; j < 16; ++j) Oacc[j] = 0.0f;

    for (int kt = 0; kt < 16; ++kt) {
        __syncthreads();
#pragma unroll
        for (int i = 0; i < 4; ++i) {
            int lin = tid + i * 256;
            int r = lin >> 4, c4 = lin & 15;
            float4 kv = *(const float4*)(kp + (size_t)(kt * 64 + r) * DH + c4 * 4);
            Ks[r][c4 * 4 + 0] = kv.x; Ks[r][c4 * 4 + 1] = kv.y;
            Ks[r][c4 * 4 + 2] = kv.z; Ks[r][c4 * 4 + 3] = kv.w;
            float4 vv = *(const float4*)(vp + (size_t)(kt * 64 + r) * DH + c4 * 4);
            Vs[r][c4 * 4 + 0] = vv.x; Vs[r][c4 * 4 + 1] = vv.y;
            Vs[r][c4 * 4 + 2] = vv.z; Vs[r][c4 * 4 + 3] = vv.w;
        }
        __syncthreads();

        float sacc[16];
#pragma unroll
        for (int j = 0; j < 16; ++j) sacc[j] = 0.0f;
        for (int k = 0; k < 64; ++k) {
            float qv = Qs[row][k];
#pragma unroll
            for (int j = 0; j < 16; ++j) sacc[j] += qv * Ks[seg * 16 + j][k];
        }
        float tmax = -3.0e38f;
#pragma unroll
        for (int j = 0; j < 16; ++j) { sacc[j] *= 0.125f; tmax = fmaxf(tmax, sacc[j]); }
        tred[row][seg] = tmax;
        __syncthreads();
        if (seg == 0) {
            float mt = fmaxf(fmaxf(tred[row][0], tred[row][1]),
                             fmaxf(tred[row][2], tred[row][3]));
            float mo = mrow[row];
            float mn = fmaxf(mo, mt);
            srow[row] = expf(mo - mn);
            mrow[row] = mn;
        }
        __syncthreads();
        float mn = mrow[row], sc = srow[row];
        float psum = 0.0f;
#pragma unroll
        for (int j = 0; j < 16; ++j) {
            float p = expf(sacc[j] - mn);
            Ks[row][seg * 16 + j] = p;
            psum += p;
        }
        tred[row][seg] = psum;
#pragma unroll
        for (int j = 0; j < 16; ++j) Oacc[j] *= sc;
        __syncthreads();
        if (seg == 0)
            lrow[row] = lrow[row] * sc +
                        (tred[row][0] + tred[row][1] + tred[row][2] + tred[row][3]);
        for (int kj = 0; kj < 64; ++kj) {
            float pv = Ks[row][kj];
#pragma unroll
            for (int j = 0; j < 16; ++j) Oacc[j] += pv * Vs[kj][seg * 16 + j];
        }
    }
    __syncthreads();
    float linv = 1.0f / lrow[row];
    int b = bh >> 4, hh = bh & 15;
    int q = qblk * 64 + row;
#pragma unroll
    for (int j = 0; j < 16; ++j)
        ctx[((size_t)(b * T + q)) * D + hh * 64 + seg * 16 + j] = Oacc[j] * linv;
}

// ---------------------------------------------------------------------------
// Persistent GRU recurrence, distributed-flag protocol (no RMW, no fences):
//  - data moves only via relaxed agent-scope atomics (bypass non-coherent L2)
//  - arrival: ONE relaxed store to the block's own padded flag (epoch number)
//  - consume: each thread polls the 4 source blocks feeding ITS staged words,
//    then issues its uncached stage loads immediately (ragged-arrival overlap)
//  - __syncthreads() after staging restores full-barrier semantics per block
//    (all 128 flags are collectively polled by the 32 thread-groups)
// ---------------------------------------------------------------------------
__global__ __launch_bounds__(256, 1) void gru_persistent(
    const float* __restrict__ w_hh, const float* __restrict__ b_hh,
    const float* __restrict__ gate_w,
    const float* __restrict__ gi, const float* __restrict__ ga,
    const float* __restrict__ attn, float* __restrict__ out,
    float* __restrict__ hbuf, float* __restrict__ hpbuf,
    unsigned* __restrict__ flags)
{
    extern __shared__ float lds[];   // [0,32768): weights; [32768,+4*1032): stage
    float* sh = lds + 32768;
    const int tid = threadIdx.x;
    const int chain = blockIdx.x & 1;
    const int pos = blockIdx.x >> 1;            // 0..127
    const int d0 = pos * DIMS_PER_BLK;

    // resident weights: rows 0..7 w_r, 8..15 w_z, 16..23 w_n, 24..31 gate_wL
#pragma unroll 4
    for (int r = 0; r < 32; ++r) {
        int which = r >> 3, j = r & 7;
        const float* src = (which < 3)
            ? (w_hh + (size_t)(which * D + d0 + j) * D)
            : (gate_w + (size_t)(d0 + j) * (2 * D));
        float4 v = *(const float4*)(src + tid * 4);
        *(float4*)(&lds[(size_t)r * 1024 + tid * 4]) = v;
    }

    const int grp = tid >> 3, kp = tid & 7;
    const int bl = grp & 3, j = grp >> 2;       // batch-in-chain, dim-in-block
    const int bg = chain * 4 + bl;              // global batch row
    const int d = d0 + j;
    const float* wr = lds + (0 * 8 + j) * 1024;
    const float* wz = lds + (8 + j) * 1024;
    const float* wn = lds + (16 + j) * 1024;
    const float* wg = lds + (24 + j) * 1024;
    const float* hrow_sh = sh + bl * STG_PITCH;

    unsigned* flagbase = flags + (size_t)chain * NBLK_CHAIN * FLAG_STRIDE;
    const int s0 = tid >> 3;                    // first of this thread's 4 sources
    const float* hsrc  = hbuf  + (size_t)chain * 4 * D;
    const float* hpsrc = hpbuf + (size_t)chain * 4 * D;

    const float bhr = b_hh[d], bhz = b_hh[D + d], bhn = b_hh[2 * D + d];

    unsigned bar = 0;                 // completed-phase epoch
    float hpv = 0.0f;                 // own-dim h' carried A->B in register

#define POLL_AND_STAGE(SRC)                                                   \
    {                                                                         \
        for (;;) {                                                            \
            unsigned a0 = __hip_atomic_load(flagbase + (s0     ) * FLAG_STRIDE,\
                              __ATOMIC_RELAXED, __HIP_MEMORY_SCOPE_AGENT);    \
            unsigned a1 = __hip_atomic_load(flagbase + (s0 + 32) * FLAG_STRIDE,\
                              __ATOMIC_RELAXED, __HIP_MEMORY_SCOPE_AGENT);    \
            unsigned a2 = __hip_atomic_load(flagbase + (s0 + 64) * FLAG_STRIDE,\
                              __ATOMIC_RELAXED, __HIP_MEMORY_SCOPE_AGENT);    \
            unsigned a3 = __hip_atomic_load(flagbase + (s0 + 96) * FLAG_STRIDE,\
                              __ATOMIC_RELAXED, __HIP_MEMORY_SCOPE_AGENT);    \
            if (a0 >= bar && a1 >= bar && a2 >= bar && a3 >= bar) break;      \
        }                                                                     \
        float r_[16];                                                         \
        _Pragma("unroll")                                                     \
        for (int q = 0; q < 16; ++q)                                          \
            r_[q] = __hip_atomic_load((SRC) + q * 256 + tid,                  \
                        __ATOMIC_RELAXED, __HIP_MEMORY_SCOPE_AGENT);          \
        _Pragma("unroll")                                                     \
        for (int q = 0; q < 16; ++q) {                                        \
            int w = q * 256 + tid;                                            \
            sh[(w >> 10) * STG_PITCH + (w & 1023)] = r_[q];                   \
        }                                                                     \
    }                                                                         \
    __syncthreads();

    for (int t = 0; t < T; ++t) {
        const float* gib = gi + ((size_t)bg * T + t) * (3 * D);
        const float gav_a = ga[((size_t)bg * T + t) * D + d];
        const float av = attn[((size_t)bg * T + t) * D + d];
        for (int s = 0; s < NSTEPS; ++s) {
            // ---- phase A: stage h, gh = h @ w_hh^T
            POLL_AND_STAGE(hsrc)
            float ar = 0.0f, az = 0.0f, an = 0.0f;
#pragma unroll 8
            for (int m = 0; m < 32; ++m) {
                int kk = (kp + 8 * m) * 4;
                float4 hv = *(const float4*)(hrow_sh + kk);
                float4 w0 = *(const float4*)(wr + kk);
                float4 w1 = *(const float4*)(wz + kk);
                float4 w2 = *(const float4*)(wn + kk);
                ar += hv.x * w0.x + hv.y * w0.y + hv.z * w0.z + hv.w * w0.w;
                az += hv.x * w1.x + hv.y * w1.y + hv.z * w1.z + hv.w * w1.w;
                an += hv.x * w2.x + hv.y * w2.y + hv.z * w2.z + hv.w * w2.w;
            }
#pragma unroll
            for (int off = 1; off < 8; off <<= 1) {
                ar += __shfl_xor(ar, off);
                az += __shfl_xor(az, off);
                an += __shfl_xor(an, off);
            }
            if (kp == 0) {
                float r_ = sigmoidf_(gib[d] + ar + bhr);
                float z_ = sigmoidf_(gib[D + d] + az + bhz);
                float n_ = tanhf(gib[2 * D + d] + r_ * (an + bhn));
                float ho = hrow_sh[d];
                hpv = (1.0f - z_) * n_ + z_ * ho;
                __hip_atomic_store(hpbuf + (size_t)bg * D + d, hpv,
                                   __ATOMIC_RELAXED, __HIP_MEMORY_SCOPE_AGENT);
            }
            asm volatile("s_waitcnt vmcnt(0)" ::: "memory");
            __syncthreads();
            ++bar;
            if (tid == 0)
                __hip_atomic_store(flagbase + pos * FLAG_STRIDE, bar,
                                   __ATOMIC_RELAXED, __HIP_MEMORY_SCOPE_AGENT);

            // ---- phase B: stage hp, g = sigmoid(hp @ gwL^T + ga)
            POLL_AND_STAGE(hpsrc)
            float ag = 0.0f;
#pragma unroll 8
            for (int m = 0; m < 32; ++m) {
                int kk = (kp + 8 * m) * 4;
                float4 hv = *(const float4*)(hrow_sh + kk);
                float4 wv = *(const float4*)(wg + kk);
                ag += hv.x * wv.x + hv.y * wv.y + hv.z * wv.z + hv.w * wv.w;
            }
#pragma unroll
            for (int off = 1; off < 8; off <<= 1) ag += __shfl_xor(ag, off);
            if (kp == 0) {
                float g = sigmoidf_(ag + gav_a);
                float hn = g * hpv + (1.0f - g) * av;
                __hip_atomic_store(hbuf + (size_t)bg * D + d, hn,
                                   __ATOMIC_RELAXED, __HIP_MEMORY_SCOPE_AGENT);
                if (s == NSTEPS - 1) out[((size_t)bg * T + t) * D + d] = hn;
            }
            asm volatile("s_waitcnt vmcnt(0)" ::: "memory");
            __syncthreads();
            ++bar;
            if (tid == 0)
                __hip_atomic_store(flagbase + pos * FLAG_STRIDE, bar,
                                   __ATOMIC_RELAXED, __HIP_MEMORY_SCOPE_AGENT);
        }
    }
#undef POLL_AND_STAGE
}

// ---------------------------------------------------------------------------
extern "C" void kernel_launch(void* const* d_in, const int* in_sizes, int n_in,
                              void* d_out, int out_size, void* d_ws, size_t ws_size,
                              hipStream_t stream)
{
    const float* x          = (const float*)d_in[0];
    const float* in_proj_w  = (const float*)d_in[1];
    const float* in_proj_b  = (const float*)d_in[2];
    const float* out_proj_w = (const float*)d_in[3];
    const float* out_proj_b = (const float*)d_in[4];
    const float* w_ih       = (const float*)d_in[5];
    const float* w_hh       = (const float*)d_in[6];
    const float* b_ih       = (const float*)d_in[7];
    const float* b_hh       = (const float*)d_in[8];
    const float* gate_w     = (const float*)d_in[9];
    const float* gate_b     = (const float*)d_in[10];
    float* out = (float*)d_out;

    float* ws = (float*)d_ws;
    const size_t S1 = (size_t)B * H * T * DH;   // 8,388,608 floats
    float* qb   = ws;
    float* kb   = ws + S1;
    float* vb   = ws + 2 * S1;
    float* ctx  = ws + 3 * S1;
    float* attn = ws + 4 * S1;
    float* ga   = ws + 5 * S1;
    float* gi   = ws;                           // overlaps q/k/v
    float* hbuf  = ws + 6 * S1;
    float* hpbuf = hbuf + B * D;
    unsigned* flags = (unsigned*)(hpbuf + B * D);  // 2 chains *128 flags *64B

    dim3 blk(256);

    gemm_kernel<1><<<dim3(128, 48), blk, 0, stream>>>(
        x, in_proj_w, in_proj_b, nullptr, B * T, 3 * D, D, D, 0, qb, kb, vb);
    attn_kernel<<<dim3(2048), blk, 0, stream>>>(qb, kb, vb, ctx);
    gemm_kernel<0><<<dim3(128, 16), blk, 0, stream>>>(
        ctx, out_proj_w, out_proj_b, attn, B * T, D, D, D, 0,
        nullptr, nullptr, nullptr);
    gemm_kernel<0><<<dim3(128, 16), blk, 0, stream>>>(
        attn, gate_w, gate_b, ga, B * T, D, D, 2 * D, D,
        nullptr, nullptr, nullptr);
    gemm_kernel<0><<<dim3(128, 48), blk, 0, stream>>>(
        x, w_ih, b_ih, gi, B * T, 3 * D, D, D, 0,
        nullptr, nullptr, nullptr);

    // zero h, hp, and flags every launch (graph-replay deterministic)
    hipMemsetAsync(hbuf, 0,
                   (2 * (size_t)B * D) * sizeof(float) +
                   NCHAIN * NBLK_CHAIN * FLAG_STRIDE * sizeof(unsigned),
                   stream);

    const int LDS_BYTES = (32 * 1024 + 4 * STG_PITCH) * 4;   // 147,584
    static bool attr_done = false;
    if (!attr_done) {
        hipFuncSetAttribute((const void*)gru_persistent,
                            hipFuncAttributeMaxDynamicSharedMemorySize, LDS_BYTES);
        attr_done = true;
    }
    gru_persistent<<<dim3(NCHAIN * NBLK_CHAIN), blk, LDS_BYTES, stream>>>(
        w_hh, b_hh, gate_w, gi, ga, attn, out, hbuf, hpbuf, flags);
}